// Round 1
// baseline (333.327 us; speedup 1.0000x reference)
//
#include <hip/hip_runtime.h>

// SPU(z) = z^2 - 0.5           for z >= 0
//        = sigmoid(-z) - 1     for z <  0
// sigmoid(-z) - 1 = 1/(1+e^z) - 1 = -e^z/(1+e^z)   (cancellation-free form)
__device__ __forceinline__ float spu(float z) {
    float e   = expf(z);                 // z<0 path: e in (0,1), no overflow
    float neg = -e / (1.0f + e);
    float pos = fmaf(z, z, -0.5f);
    return (z >= 0.0f) ? pos : neg;
}

__global__ __launch_bounds__(256)
void spu_box_kernel(const float* __restrict__ x,
                    const float* __restrict__ l_in,
                    const float* __restrict__ u_in,
                    float* __restrict__ x_out,
                    float* __restrict__ l_out,
                    float* __restrict__ u_out,
                    int n4)                  // number of float4 groups
{
    int i = blockIdx.x * blockDim.x + threadIdx.x;
    if (i >= n4) return;

    const float4* x4 = (const float4*)x;
    const float4* l4 = (const float4*)l_in;
    const float4* u4 = (const float4*)u_in;

    float4 xv = x4[i];
    float4 lv = l4[i];
    float4 uv = u4[i];

    float4 xo, lo, uo;

    #pragma unroll
    for (int k = 0; k < 4; ++k) {
        float xs = ((const float*)&xv)[k];
        float ls = ((const float*)&lv)[k];
        float us = ((const float*)&uv)[k];

        float sx = spu(xs);
        float sl = spu(ls);
        float su = spu(us);

        // l_out: l>=0 -> spu(l); else u<=0 -> spu(u); else -0.5
        float lres = (ls >= 0.0f) ? sl : ((us <= 0.0f) ? su : -0.5f);
        // u_out: u<=0 -> spu(l); else spu(u)
        float ures = (us <= 0.0f) ? sl : su;

        ((float*)&xo)[k] = sx;
        ((float*)&lo)[k] = lres;
        ((float*)&uo)[k] = ures;
    }

    ((float4*)x_out)[i] = xo;
    ((float4*)l_out)[i] = lo;
    ((float4*)u_out)[i] = uo;
}

// Scalar tail (n not divisible by 4) — not hit for DIM=16777216 but kept safe.
__global__ void spu_box_tail(const float* __restrict__ x,
                             const float* __restrict__ l_in,
                             const float* __restrict__ u_in,
                             float* __restrict__ x_out,
                             float* __restrict__ l_out,
                             float* __restrict__ u_out,
                             int start, int n)
{
    int i = start + blockIdx.x * blockDim.x + threadIdx.x;
    if (i >= n) return;
    float xs = x[i], ls = l_in[i], us = u_in[i];
    float sx = spu(xs), sl = spu(ls), su = spu(us);
    x_out[i] = sx;
    l_out[i] = (ls >= 0.0f) ? sl : ((us <= 0.0f) ? su : -0.5f);
    u_out[i] = (us <= 0.0f) ? sl : su;
}

extern "C" void kernel_launch(void* const* d_in, const int* in_sizes, int n_in,
                              void* d_out, int out_size, void* d_ws, size_t ws_size,
                              hipStream_t stream) {
    const float* x    = (const float*)d_in[0];
    const float* l_in = (const float*)d_in[1];
    const float* u_in = (const float*)d_in[2];

    const int n = in_sizes[0];           // 16777216
    float* out   = (float*)d_out;        // [x_out | l_out | u_out], each n floats
    float* x_out = out;
    float* l_out = out + n;
    float* u_out = out + 2 * (size_t)n;

    const int n4 = n / 4;
    const int block = 256;
    const int grid = (n4 + block - 1) / block;
    spu_box_kernel<<<grid, block, 0, stream>>>(x, l_in, u_in, x_out, l_out, u_out, n4);

    const int tail_start = n4 * 4;
    if (tail_start < n) {
        const int tail = n - tail_start;
        spu_box_tail<<<(tail + 63) / 64, 64, 0, stream>>>(x, l_in, u_in,
                                                          x_out, l_out, u_out,
                                                          tail_start, n);
    }
}